// Round 1
// baseline (364.127 us; speedup 1.0000x reference)
//
#include <hip/hip_runtime.h>
#include <math.h>

// EdgeFeaturizer: per-row top-12 smallest of 8192x8192 fp32 + RBF features.
// d_out layout (float32): [8192*12*2] edge_index as float values, then
// [8192*12*50] features.

#define N_ATOMS 8192
#define K 12
#define NBINS 50
#define CAP 1024
#define BLOCK 256
#define MAX_RADIUS 8.0f
#define CAND_T 0.01f   // expected ~82 candidates/row; fallback is exact anyway

__global__ __launch_bounds__(BLOCK) void edge_kernel(const float* __restrict__ dm,
                                                     float* __restrict__ out) {
    const int row = blockIdx.x;
    const int tid = threadIdx.x;
    const float* rowp = dm + (size_t)row * N_ATOMS;
    const float4* row4 = (const float4*)rowp;

    __shared__ unsigned long long s_keys[CAP];
    __shared__ int s_count;
    __shared__ int s_selidx[K];
    __shared__ float s_seldist[K];
    __shared__ unsigned long long s_red[BLOCK];

    if (tid == 0) s_count = 0;
    __syncthreads();

    // ---- candidate scan: coalesced float4, push d < CAND_T into LDS ----
    #pragma unroll
    for (int j = 0; j < N_ATOMS / (BLOCK * 4); ++j) {
        int v4 = tid + j * BLOCK;
        float4 v = row4[v4];
        int base = v4 * 4;
        float vals[4] = {v.x, v.y, v.z, v.w};
        #pragma unroll
        for (int c = 0; c < 4; ++c) {
            float d = vals[c];
            if (d < CAND_T) {
                int pos = atomicAdd(&s_count, 1);
                if (pos < CAP) {
                    unsigned long long fb = (unsigned long long)__float_as_uint(d);
                    s_keys[pos] = (fb << 32) | (unsigned int)(base + c);
                }
            }
        }
    }
    __syncthreads();
    int count = s_count;  // block-uniform

    if (count >= K && count <= CAP) {
        // ---- O(count^2) rank selection: rank = #keys strictly smaller ----
        // key = (float_bits << 32) | idx  => order == (dist asc, idx asc),
        // exactly jax.lax.top_k(-masked) tie-breaking. Keys are unique.
        for (int j = tid; j < count; j += BLOCK) {
            unsigned long long kj = s_keys[j];
            int rank = 0;
            for (int m = 0; m < count; ++m)
                rank += (s_keys[m] < kj) ? 1 : 0;
            if (rank < K) {
                s_selidx[rank] = (int)(kj & 0xFFFFFFFFull);
                s_seldist[rank] = __uint_as_float((unsigned int)(kj >> 32));
            }
        }
    } else {
        // ---- exact fallback (never taken on this input): 12 sequential
        // block-wide min-reductions over masked keys, strictly > last ----
        unsigned long long last = 0ULL;
        for (int r = 0; r < K; ++r) {
            unsigned long long best = ~0ULL;
            for (int j = 0; j < N_ATOMS / (BLOCK * 4); ++j) {
                int v4 = tid + j * BLOCK;
                float4 v = row4[v4];
                int base = v4 * 4;
                float vals[4] = {v.x, v.y, v.z, v.w};
                #pragma unroll
                for (int c = 0; c < 4; ++c) {
                    float d = vals[c];
                    float md = (d <= MAX_RADIUS) ? d : __uint_as_float(0x7F800000u);
                    unsigned long long key =
                        ((unsigned long long)__float_as_uint(md) << 32) |
                        (unsigned int)(base + c);
                    bool ok = (r == 0) || (key > last);
                    if (ok && key < best) best = key;
                }
            }
            s_red[tid] = best;
            __syncthreads();
            for (int s = BLOCK / 2; s > 0; s >>= 1) {
                if (tid < s) {
                    if (s_red[tid + s] < s_red[tid]) s_red[tid] = s_red[tid + s];
                }
                __syncthreads();
            }
            unsigned long long sel = s_red[0];
            if (tid == 0) {
                int idx = (int)(sel & 0xFFFFFFFFull);
                s_selidx[r] = idx;
                s_seldist[r] = rowp[idx];  // take_along_axis uses ORIGINAL dm
            }
            last = sel;
            __syncthreads();
        }
    }
    __syncthreads();

    // ---- write edge_index (as float values) ----
    float* out_ei = out;
    float* out_ef = out + (size_t)N_ATOMS * K * 2;
    if (tid < 2 * K) {
        int r = tid >> 1, comp = tid & 1;
        out_ei[((size_t)row * K + r) * 2 + comp] =
            comp ? (float)s_selidx[r] : (float)row;
    }

    // ---- RBF features: centers = b/49, z = (d-c)/0.2, exp(-z^2/2) ----
    for (int t = tid; t < K * NBINS; t += BLOCK) {
        int r = t / NBINS, b = t - r * NBINS;
        float d = s_seldist[r];
        float c = (float)b / 49.0f;
        float z = (d - c) / 0.2f;
        out_ef[((size_t)row * K + r) * NBINS + b] = __expf(-0.5f * z * z);
    }
}

extern "C" void kernel_launch(void* const* d_in, const int* in_sizes, int n_in,
                              void* d_out, int out_size, void* d_ws, size_t ws_size,
                              hipStream_t stream) {
    const float* dm = (const float*)d_in[0];
    float* out = (float*)d_out;
    edge_kernel<<<N_ATOMS, BLOCK, 0, stream>>>(dm, out);
}